// Round 7
// baseline (427.210 us; speedup 1.0000x reference)
//
#include <hip/hip_runtime.h>
#include <cstdint>
#include <cstddef>

typedef unsigned short u16;
typedef short v8s __attribute__((ext_vector_type(8)));
typedef float v16f __attribute__((ext_vector_type(16)));

constexpr int SEQ = 4096;
constexpr int FEAT = 2048;
constexpr int F3 = 6144;

// ---------- helpers ----------

__device__ __forceinline__ u16 f2bf(float f) {
  union { float f; uint32_t u; } v; v.f = f;
  uint32_t r = v.u + 0x7FFFu + ((v.u >> 16) & 1u);  // round-to-nearest-even
  return (u16)(r >> 16);
}

__device__ __forceinline__ float bf2f(u16 s) {
  union { uint32_t u; float f; } v; v.u = ((uint32_t)s) << 16;
  return v.f;
}

// async global->LDS, 16B per lane; lds dest is wave-uniform base (HW: base+lane*16)
__device__ __forceinline__ void gld_lds16(const u16* g, u16* l) {
  __builtin_amdgcn_global_load_lds(
      (const __attribute__((address_space(1))) void*)g,
      (__attribute__((address_space(3))) void*)l, 16, 0, 0);
}

// ---------- conversion / transpose / reduce ----------

__global__ void cvt_f32_bf16(const float* __restrict__ in, u16* __restrict__ out, int n8) {
  int i = blockIdx.x * 256 + threadIdx.x;
  if (i >= n8) return;
  const float4* p = (const float4*)in + (size_t)i * 2;
  float4 a = p[0], b = p[1];
  union { u16 s[8]; uint4 v; } u;
  u.s[0] = f2bf(a.x); u.s[1] = f2bf(a.y); u.s[2] = f2bf(a.z); u.s[3] = f2bf(a.w);
  u.s[4] = f2bf(b.x); u.s[5] = f2bf(b.y); u.s[6] = f2bf(b.z); u.s[7] = f2bf(b.w);
  *(uint4*)(out + (size_t)i * 8) = u.v;
}

__global__ void transp_f2b(const float* __restrict__ in, int ldin,
                           u16* __restrict__ out, int ldout) {
  __shared__ float tile[32][33];
  int c0 = blockIdx.x * 32, r0 = blockIdx.y * 32;
  int tx = threadIdx.x, ty = threadIdx.y;
#pragma unroll
  for (int p = 0; p < 4; ++p)
    tile[ty + 8 * p][tx] = in[(size_t)(r0 + ty + 8 * p) * ldin + c0 + tx];
  __syncthreads();
#pragma unroll
  for (int p = 0; p < 4; ++p)
    out[(size_t)(c0 + ty + 8 * p) * ldout + r0 + tx] = f2bf(tile[tx][ty + 8 * p]);
}

__global__ void transp_b2b(const u16* __restrict__ in, int ldin,
                           u16* __restrict__ out, int ldout) {
  __shared__ u16 tile[32][33];
  int c0 = blockIdx.x * 32, r0 = blockIdx.y * 32;
  int tx = threadIdx.x, ty = threadIdx.y;
#pragma unroll
  for (int p = 0; p < 4; ++p)
    tile[ty + 8 * p][tx] = in[(size_t)(r0 + ty + 8 * p) * ldin + c0 + tx];
  __syncthreads();
#pragma unroll
  for (int p = 0; p < 4; ++p)
    out[(size_t)(c0 + ty + 8 * p) * ldout + r0 + tx] = tile[tx][ty + 8 * p];
}

// out = p0 + p1 (fp32), float4-vectorized. Replaces memset+atomic split-K combine.
__global__ void reduce_add(const float* __restrict__ p0, const float* __restrict__ p1,
                           float* __restrict__ out, int n4) {
  int i = blockIdx.x * 256 + threadIdx.x;
  if (i >= n4) return;
  float4 a = ((const float4*)p0)[i];
  float4 b = ((const float4*)p1)[i];
  float4 r; r.x = a.x + b.x; r.y = a.y + b.y; r.z = a.z + b.z; r.w = a.w + b.w;
  ((float4*)out)[i] = r;
}

// ---------- GEMM: C[M,N] = A[M,K] * B[N,K]^T (bf16, k contiguous) ----------
// BM=BN=128, BK=64 as 2x(128x32) sub-tiles (4096 u16 each). 256 thr = 4 waves
// in 2x2 of 64x64; each wave 2x2 of 32x32 via v_mfma_f32_32x32x16_bf16
// (r7: 8 MFMA x 8cyc per k32 vs 16 x 4.85 -> -18% MFMA pipe; m119 ceiling 2495 TF).
// A frag: m=lane&31, k=(lane>>5)*8+j; B symmetric on N. C/D: col=lane&31,
// row=(reg&3)+8*(reg>>2)+4*(lane>>5) [m74/m101 verified].
// LDS chunk swizzle (r4, verified conflicts->0): chunk (row,col8) at
// col8'=(col8+(row>>1))&3; staging inverts; read-side swl=(ln31>>1)&3.
// MODE: 0 = normal grid (GEMM1)
//       1 = compact lower-triangular grid, split-K z=2, DISJOINT bf16 buffers
//       2 = causal split-K z=2 (half=(bi+1)*64), DISJOINT fp32 buffers (r7:
//           plain stores; reduce_add combines — no atomics)
template<int OUTBF, int ADDB, int MODE>
__global__ __launch_bounds__(256) void gemm_bt(
    const u16* __restrict__ A, int lda,
    const u16* __restrict__ B, int ldb,
    void* __restrict__ Cv, int ldc,
    int K, const float* __restrict__ bias, float scale) {
  int bi, bj, ks, ke;
  if (MODE == 1) {
    const int t = blockIdx.x;
    bi = (int)((sqrtf(8.f * t + 1.f) - 1.f) * 0.5f);
    while ((bi + 1) * (bi + 2) / 2 <= t) ++bi;
    while (bi * (bi + 1) / 2 > t) --bi;
    bj = t - bi * (bi + 1) / 2;
    const int half = K >> 1;                 // 1024
    ks = blockIdx.z * half; ke = ks + half;
    Cv = (void*)((u16*)Cv + (size_t)blockIdx.z * SEQ * SEQ);   // disjoint bf16
  } else if (MODE == 2) {
    bi = blockIdx.y; bj = blockIdx.x;
    const int half = (bi + 1) * 64;          // kend/2, multiple of 64
    ks = blockIdx.z * half; ke = ks + half;
    Cv = (void*)((float*)Cv + (size_t)blockIdx.z * SEQ * FEAT); // disjoint fp32
  } else {
    bi = blockIdx.y; bj = blockIdx.x;
    ks = 0; ke = K;
  }
  const int i0 = bi * 128, j0 = bj * 128;

  __shared__ u16 As[128 * 64];   // sub-tile s at element offset s*4096
  __shared__ u16 Bs[128 * 64];

  const int t = threadIdx.x;
  const int w = t >> 6, l = t & 63;
  const int wr = w >> 1, wc = w & 1;
  const int ln31 = l & 31, lk = l >> 5;      // row/col in 32-tile; k-half select
  const int swl = (ln31 >> 1) & 3;           // read-side swizzle addend

  v16f acc[2][2];
#pragma unroll
  for (int a = 0; a < 2; ++a)
#pragma unroll
    for (int b = 0; b < 2; ++b)
#pragma unroll
      for (int r = 0; r < 16; ++r)
        acc[a][b][r] = 0.f;

  // staging: thread t handles chunks c=t and c=t+256 of each 128x32 sub-tile.
  // chunk c -> LDS bytes [c*16, c*16+16) (fixed by global_load_lds);
  // global source: row = c>>2, col8 = ((c&3) - ((c>>3)&3)) & 3  (swizzle inverse)
  const int c1 = t + 256;
  const int r0c = t >> 2, o0 = ((((t & 3) - ((t >> 3) & 3)) & 3)) * 8;
  const int r1c = c1 >> 2, o1 = ((((c1 & 3) - ((c1 >> 3) & 3)) & 3)) * 8;
  const u16* Ag0 = A + (size_t)(i0 + r0c) * lda + o0;
  const u16* Ag1 = A + (size_t)(i0 + r1c) * lda + o1;
  const u16* Bg0 = B + (size_t)(j0 + r0c) * ldb + o0;
  const u16* Bg1 = B + (size_t)(j0 + r1c) * ldb + o1;
  u16* Al0 = &As[w * 512];
  u16* Al1 = &As[w * 512 + 2048];
  u16* Bl0 = &Bs[w * 512];
  u16* Bl1 = &Bs[w * 512 + 2048];

  for (int k0 = ks; k0 < ke; k0 += 64) {
    gld_lds16(Ag0 + k0, Al0);
    gld_lds16(Ag1 + k0, Al1);
    gld_lds16(Bg0 + k0, Bl0);
    gld_lds16(Bg1 + k0, Bl1);
    gld_lds16(Ag0 + k0 + 32, Al0 + 4096);
    gld_lds16(Ag1 + k0 + 32, Al1 + 4096);
    gld_lds16(Bg0 + k0 + 32, Bl0 + 4096);
    gld_lds16(Bg1 + k0 + 32, Bl1 + 4096);
    __syncthreads();  // drains vmcnt(0): staged data visible

#pragma unroll
    for (int s = 0; s < 2; ++s) {
#pragma unroll
      for (int kk = 0; kk < 2; ++kk) {
        v8s af[2], bfr[2];
#pragma unroll
        for (int mi = 0; mi < 2; ++mi) {
          const int R = wr * 64 + mi * 32 + ln31;
          af[mi] = *(const v8s*)&As[s * 4096 + R * 32 + ((kk * 2 + lk + swl) & 3) * 8];
        }
#pragma unroll
        for (int ni = 0; ni < 2; ++ni) {
          const int R = wc * 64 + ni * 32 + ln31;
          bfr[ni] = *(const v8s*)&Bs[s * 4096 + R * 32 + ((kk * 2 + lk + swl) & 3) * 8];
        }
#pragma unroll
        for (int mi = 0; mi < 2; ++mi)
#pragma unroll
          for (int ni = 0; ni < 2; ++ni)
            acc[mi][ni] = __builtin_amdgcn_mfma_f32_32x32x16_bf16(
                af[mi], bfr[ni], acc[mi][ni], 0, 0, 0);
      }
    }
    __syncthreads();  // LDS reads done before next stage
  }

  // epilogue: 32x32 C/D layout col=lane&31, row=(reg&3)+8*(reg>>2)+4*lk
#pragma unroll
  for (int mi = 0; mi < 2; ++mi) {
#pragma unroll
    for (int ni = 0; ni < 2; ++ni) {
      const int cc = j0 + wc * 64 + ni * 32 + ln31;
      const float badd = ADDB ? bias[cc] : 0.f;
#pragma unroll
      for (int reg = 0; reg < 16; ++reg) {
        const int rr = i0 + wr * 64 + mi * 32 + (reg & 3) + 8 * (reg >> 2) + 4 * lk;
        float v = acc[mi][ni][reg] * scale + badd;
        if (OUTBF) ((u16*)Cv)[(size_t)rr * ldc + cc] = f2bf(v);
        else       ((float*)Cv)[(size_t)rr * ldc + cc] = v;
      }
    }
  }
}

// ---------- row softmax with causal + padding mask ----------
// scores come as two bf16 split-K partials: s(i,j) = sc0[i,j] + sc1[i,j]
__global__ __launch_bounds__(256) void softmax_rows(
    const u16* __restrict__ S0, const u16* __restrict__ S1,
    u16* __restrict__ att, const int* __restrict__ npad_p) {
  const int i = blockIdx.x;
  const int np = *npad_p;
  const int kend = ((i >> 7) + 1) << 7;
  const u16* r0 = S0 + (size_t)i * SEQ;
  const u16* r1 = S1 + (size_t)i * SEQ;
  u16* arow = att + (size_t)i * SEQ;
  const int t = threadIdx.x;

  float m = -3.0e38f, s = 0.f;
  for (int j = np + t; j <= i; j += 256) {
    float v = bf2f(r0[j]) + bf2f(r1[j]);
    if (v > m) { s = s * __expf(m - v) + 1.f; m = v; }
    else       { s += __expf(v - m); }
  }
#pragma unroll
  for (int off = 32; off > 0; off >>= 1) {
    float mo = __shfl_xor(m, off);
    float so = __shfl_xor(s, off);
    float M = fmaxf(m, mo);
    s = s * __expf(m - M) + so * __expf(mo - M);
    m = M;
  }
  __shared__ float sm[4], ss[4];
  const int w = t >> 6, l = t & 63;
  if (l == 0) { sm[w] = m; ss[w] = s; }
  __syncthreads();
  const float M = fmaxf(fmaxf(sm[0], sm[1]), fmaxf(sm[2], sm[3]));
  const float Ssum = ss[0] * __expf(sm[0] - M) + ss[1] * __expf(sm[1] - M) +
                     ss[2] * __expf(sm[2] - M) + ss[3] * __expf(sm[3] - M);
  const float inv = 1.f / Ssum;  // padded rows masked to 0 below; inv unused there

  for (int j0b = t * 8; j0b < kend; j0b += 2048) {
    union { u16 s8[8]; uint4 v; } u;
#pragma unroll
    for (int q = 0; q < 8; ++q) {
      const int j = j0b + q;
      float a = 0.f;
      if (j >= np && j <= i)
        a = __expf(bf2f(r0[j]) + bf2f(r1[j]) - M) * inv;
      u.s8[q] = f2bf(a);
    }
    *(uint4*)(arow + j0b) = u.v;
  }
}

// ---------- launch ----------

extern "C" void kernel_launch(void* const* d_in, const int* in_sizes, int n_in,
                              void* d_out, int out_size, void* d_ws, size_t ws_size,
                              hipStream_t stream) {
  const float* x = (const float*)d_in[0];
  const float* W = (const float*)d_in[1];
  const float* b = (const float*)d_in[2];
  const int* npad = (const int*)d_in[3];
  float* out = (float*)d_out;

  // workspace:
  // [xb 16.8 | Wt 25.2] reused as att 33.6 ][ qkvb 50.3 ][ vt 16.8 ][ sc0 33.6 | sc1 33.6 ] MB
  // sc0/sc1 hold bf16 score partials for softmax, then are reused as the two
  // fp32 GEMM3 output partials (each exactly SEQ*FEAT*4 = 33.6 MB).
  char* p = (char*)d_ws;
  u16* xb = (u16*)p;
  u16* Wt = (u16*)(p + (size_t)SEQ * FEAT * 2);
  u16* att = (u16*)p;
  p += (size_t)SEQ * FEAT * 2 + (size_t)F3 * FEAT * 2;
  u16* qkvb = (u16*)p;  p += (size_t)SEQ * F3 * 2;
  u16* vt   = (u16*)p;  p += (size_t)FEAT * SEQ * 2;
  u16* sc0  = (u16*)p;  p += (size_t)SEQ * SEQ * 2;   // bf16 split-K partial 0
  u16* sc1  = (u16*)p;  p += (size_t)SEQ * SEQ * 2;   // bf16 split-K partial 1
  float* op = (float*)sc0;                            // fp32 out-partials (2x)
  if (ws_size < (size_t)(p - (char*)d_ws)) return;

  const float scale = 0.02209708691207961f;  // 1/sqrt(2048)

  cvt_f32_bf16<<<SEQ * FEAT / 8 / 256, 256, 0, stream>>>(x, xb, SEQ * FEAT / 8);
  transp_f2b<<<dim3(F3 / 32, FEAT / 32), dim3(32, 8), 0, stream>>>(W, F3, Wt, FEAT);
  // qkv = x @ W + b (bf16)
  gemm_bt<1, 1, 0><<<dim3(F3 / 128, SEQ / 128), 256, 0, stream>>>(
      xb, FEAT, Wt, FEAT, (void*)qkvb, F3, FEAT, b, 1.0f);
  transp_b2b<<<dim3(FEAT / 32, SEQ / 32), dim3(32, 8), 0, stream>>>(
      qkvb + 2 * FEAT, F3, vt, SEQ);
  // scores = (q @ k^T) / sqrt(F): triangular grid x split-K=2 -> sc0/sc1 bf16
  gemm_bt<1, 0, 1><<<dim3(32 * 33 / 2, 1, 2), 256, 0, stream>>>(
      qkvb, F3, qkvb + FEAT, F3, (void*)sc0, SEQ, FEAT, nullptr, scale);
  softmax_rows<<<SEQ, 256, 0, stream>>>(sc0, sc1, att, npad);
  // out partials = att @ v: causal split-K=2, disjoint fp32 buffers (no atomics)
  gemm_bt<0, 0, 2><<<dim3(FEAT / 128, SEQ / 128, 2), 256, 0, stream>>>(
      att, SEQ, vt, SEQ, (void*)op, FEAT, 0, nullptr, 1.0f);
  // out = p0 + p1
  reduce_add<<<SEQ * FEAT / 4 / 256, 256, 0, stream>>>(
      op, op + (size_t)SEQ * FEAT, out, SEQ * FEAT / 4);
}

// Round 8
// 426.372 us; speedup vs baseline: 1.0020x; 1.0020x over previous
//
#include <hip/hip_runtime.h>
#include <cstdint>
#include <cstddef>

typedef unsigned short u16;
typedef short v8s __attribute__((ext_vector_type(8)));
typedef float v16f __attribute__((ext_vector_type(16)));

constexpr int SEQ = 4096;
constexpr int FEAT = 2048;
constexpr int F3 = 6144;

// ---------- helpers ----------

__device__ __forceinline__ u16 f2bf(float f) {
  union { float f; uint32_t u; } v; v.f = f;
  uint32_t r = v.u + 0x7FFFu + ((v.u >> 16) & 1u);  // round-to-nearest-even
  return (u16)(r >> 16);
}

__device__ __forceinline__ float bf2f(u16 s) {
  union { uint32_t u; float f; } v; v.u = ((uint32_t)s) << 16;
  return v.f;
}

// LDS chunk swizzle addend (r8): g(r) = {0,0,2,2,1,1,3,3}[r&7].
// Derived to be conflict-free under BOTH candidate LDS phase models
// (aligned 8-lane groups, and quads paired across lane halves) — r7's
// (r>>1)&3 was clean under the first but 2-way under the second (measured
// 1.258e7 conflict cycles, identical to unswizzled r3).
__device__ __forceinline__ int swz(int r) {
  return (((r >> 1) & 1) << 1) | ((r >> 2) & 1);
}

// async global->LDS, 16B per lane; lds dest is wave-uniform base (HW: base+lane*16)
__device__ __forceinline__ void gld_lds16(const u16* g, u16* l) {
  __builtin_amdgcn_global_load_lds(
      (const __attribute__((address_space(1))) void*)g,
      (__attribute__((address_space(3))) void*)l, 16, 0, 0);
}

// ---------- conversion / transpose / reduce ----------

__global__ void cvt_f32_bf16(const float* __restrict__ in, u16* __restrict__ out, int n8) {
  int i = blockIdx.x * 256 + threadIdx.x;
  if (i >= n8) return;
  const float4* p = (const float4*)in + (size_t)i * 2;
  float4 a = p[0], b = p[1];
  union { u16 s[8]; uint4 v; } u;
  u.s[0] = f2bf(a.x); u.s[1] = f2bf(a.y); u.s[2] = f2bf(a.z); u.s[3] = f2bf(a.w);
  u.s[4] = f2bf(b.x); u.s[5] = f2bf(b.y); u.s[6] = f2bf(b.z); u.s[7] = f2bf(b.w);
  *(uint4*)(out + (size_t)i * 8) = u.v;
}

__global__ void transp_f2b(const float* __restrict__ in, int ldin,
                           u16* __restrict__ out, int ldout) {
  __shared__ float tile[32][33];
  int c0 = blockIdx.x * 32, r0 = blockIdx.y * 32;
  int tx = threadIdx.x, ty = threadIdx.y;
#pragma unroll
  for (int p = 0; p < 4; ++p)
    tile[ty + 8 * p][tx] = in[(size_t)(r0 + ty + 8 * p) * ldin + c0 + tx];
  __syncthreads();
#pragma unroll
  for (int p = 0; p < 4; ++p)
    out[(size_t)(c0 + ty + 8 * p) * ldout + r0 + tx] = f2bf(tile[tx][ty + 8 * p]);
}

__global__ void transp_b2b(const u16* __restrict__ in, int ldin,
                           u16* __restrict__ out, int ldout) {
  __shared__ u16 tile[32][33];
  int c0 = blockIdx.x * 32, r0 = blockIdx.y * 32;
  int tx = threadIdx.x, ty = threadIdx.y;
#pragma unroll
  for (int p = 0; p < 4; ++p)
    tile[ty + 8 * p][tx] = in[(size_t)(r0 + ty + 8 * p) * ldin + c0 + tx];
  __syncthreads();
#pragma unroll
  for (int p = 0; p < 4; ++p)
    out[(size_t)(c0 + ty + 8 * p) * ldout + r0 + tx] = tile[tx][ty + 8 * p];
}

// out = p0 + p1 (fp32), float4-vectorized. Split-K combine without atomics.
__global__ void reduce_add(const float* __restrict__ p0, const float* __restrict__ p1,
                           float* __restrict__ out, int n4) {
  int i = blockIdx.x * 256 + threadIdx.x;
  if (i >= n4) return;
  float4 a = ((const float4*)p0)[i];
  float4 b = ((const float4*)p1)[i];
  float4 r; r.x = a.x + b.x; r.y = a.y + b.y; r.z = a.z + b.z; r.w = a.w + b.w;
  ((float4*)out)[i] = r;
}

// ---------- GEMM: C[M,N] = A[M,K] * B[N,K]^T (bf16, k contiguous) ----------
// BM=BN=128, BK=64 as 2x(128x32) sub-tiles (4096 u16 each). 256 thr = 4 waves
// in 2x2 of 64x64; each wave 2x2 of 32x32 via v_mfma_f32_32x32x16_bf16.
// A frag: m=lane&31, k=(lane>>5)*8+j; C/D: col=lane&31,
// row=(reg&3)+8*(reg>>2)+4*(lane>>5) [m74/m101 verified].
// LDS chunk (row,col8) stored at physical col (col8+swz(row))&3; staging inverts.
// MODE: 0 = normal grid (GEMM1)
//       1 = compact lower-triangular grid over bi,bj in [1,31] (bj=0 column is
//           fully masked when n_padd>=128), split-K z=2, DISJOINT bf16 buffers
//       2 = causal split-K z=2 (half=(bi+1)*64), DISJOINT fp32 buffers
template<int OUTBF, int ADDB, int MODE>
__global__ __launch_bounds__(256) void gemm_bt(
    const u16* __restrict__ A, int lda,
    const u16* __restrict__ B, int ldb,
    void* __restrict__ Cv, int ldc,
    int K, const float* __restrict__ bias, float scale) {
  int bi, bj, ks, ke;
  if (MODE == 1) {
    const int t = blockIdx.x;            // t in [0, 31*32/2)
    int bi1 = (int)((sqrtf(8.f * t + 1.f) - 1.f) * 0.5f);
    while ((bi1 + 1) * (bi1 + 2) / 2 <= t) ++bi1;
    while (bi1 * (bi1 + 1) / 2 > t) --bi1;
    const int bj1 = t - bi1 * (bi1 + 1) / 2;
    bi = bi1 + 1; bj = bj1 + 1;          // skip bj=0 (cols < n_padd, masked)
    const int half = K >> 1;             // 1024
    ks = blockIdx.z * half; ke = ks + half;
    Cv = (void*)((u16*)Cv + (size_t)blockIdx.z * SEQ * SEQ);   // disjoint bf16
  } else if (MODE == 2) {
    bi = blockIdx.y; bj = blockIdx.x;
    const int half = (bi + 1) * 64;      // kend/2, multiple of 64
    ks = blockIdx.z * half; ke = ks + half;
    Cv = (void*)((float*)Cv + (size_t)blockIdx.z * SEQ * FEAT); // disjoint fp32
  } else {
    bi = blockIdx.y; bj = blockIdx.x;
    ks = 0; ke = K;
  }
  const int i0 = bi * 128, j0 = bj * 128;

  __shared__ u16 As[128 * 64];   // sub-tile s at element offset s*4096
  __shared__ u16 Bs[128 * 64];

  const int t = threadIdx.x;
  const int w = t >> 6, l = t & 63;
  const int wr = w >> 1, wc = w & 1;
  const int ln31 = l & 31, lk = l >> 5;      // row/col in 32-tile; k-half select
  const int swg = swz(ln31);                 // read-side swizzle addend (R&7==ln31&7)

  v16f acc[2][2];
#pragma unroll
  for (int a = 0; a < 2; ++a)
#pragma unroll
    for (int b = 0; b < 2; ++b)
#pragma unroll
      for (int r = 0; r < 16; ++r)
        acc[a][b][r] = 0.f;

  // staging: thread t handles chunks c=t and c=t+256 of each 128x32 sub-tile.
  // chunk c -> LDS bytes [c*16, c*16+16) (fixed by global_load_lds);
  // global source: row = c>>2, logical col8 = ((c&3) - swz(row)) & 3
  const int c1 = t + 256;
  const int r0c = t >> 2, o0 = (((t & 3) - swz(r0c)) & 3) * 8;
  const int r1c = c1 >> 2, o1 = (((c1 & 3) - swz(r1c)) & 3) * 8;
  const u16* Ag0 = A + (size_t)(i0 + r0c) * lda + o0;
  const u16* Ag1 = A + (size_t)(i0 + r1c) * lda + o1;
  const u16* Bg0 = B + (size_t)(j0 + r0c) * ldb + o0;
  const u16* Bg1 = B + (size_t)(j0 + r1c) * ldb + o1;
  u16* Al0 = &As[w * 512];
  u16* Al1 = &As[w * 512 + 2048];
  u16* Bl0 = &Bs[w * 512];
  u16* Bl1 = &Bs[w * 512 + 2048];

  for (int k0 = ks; k0 < ke; k0 += 64) {
    gld_lds16(Ag0 + k0, Al0);
    gld_lds16(Ag1 + k0, Al1);
    gld_lds16(Bg0 + k0, Bl0);
    gld_lds16(Bg1 + k0, Bl1);
    gld_lds16(Ag0 + k0 + 32, Al0 + 4096);
    gld_lds16(Ag1 + k0 + 32, Al1 + 4096);
    gld_lds16(Bg0 + k0 + 32, Bl0 + 4096);
    gld_lds16(Bg1 + k0 + 32, Bl1 + 4096);
    __syncthreads();  // drains vmcnt(0): staged data visible

#pragma unroll
    for (int s = 0; s < 2; ++s) {
#pragma unroll
      for (int kk = 0; kk < 2; ++kk) {
        v8s af[2], bfr[2];
#pragma unroll
        for (int mi = 0; mi < 2; ++mi) {
          const int R = wr * 64 + mi * 32 + ln31;
          af[mi] = *(const v8s*)&As[s * 4096 + R * 32 + ((kk * 2 + lk + swg) & 3) * 8];
        }
#pragma unroll
        for (int ni = 0; ni < 2; ++ni) {
          const int R = wc * 64 + ni * 32 + ln31;
          bfr[ni] = *(const v8s*)&Bs[s * 4096 + R * 32 + ((kk * 2 + lk + swg) & 3) * 8];
        }
#pragma unroll
        for (int mi = 0; mi < 2; ++mi)
#pragma unroll
          for (int ni = 0; ni < 2; ++ni)
            acc[mi][ni] = __builtin_amdgcn_mfma_f32_32x32x16_bf16(
                af[mi], bfr[ni], acc[mi][ni], 0, 0, 0);
      }
    }
    __syncthreads();  // LDS reads done before next stage
  }

  // epilogue: 32x32 C/D layout col=lane&31, row=(reg&3)+8*(reg>>2)+4*lk
#pragma unroll
  for (int mi = 0; mi < 2; ++mi) {
#pragma unroll
    for (int ni = 0; ni < 2; ++ni) {
      const int cc = j0 + wc * 64 + ni * 32 + ln31;
      const float badd = ADDB ? bias[cc] : 0.f;
#pragma unroll
      for (int reg = 0; reg < 16; ++reg) {
        const int rr = i0 + wr * 64 + mi * 32 + (reg & 3) + 8 * (reg >> 2) + 4 * lk;
        float v = acc[mi][ni][reg] * scale + badd;
        if (OUTBF) ((u16*)Cv)[(size_t)rr * ldc + cc] = f2bf(v);
        else       ((float*)Cv)[(size_t)rr * ldc + cc] = v;
      }
    }
  }
}

// ---------- row softmax with causal + padding mask ----------
// scores come as two bf16 split-K partials: s(i,j) = sc0[i,j] + sc1[i,j]
// (scores only guaranteed valid for j in [n_padd, i]; loads are guarded)
__global__ __launch_bounds__(256) void softmax_rows(
    const u16* __restrict__ S0, const u16* __restrict__ S1,
    u16* __restrict__ att, const int* __restrict__ npad_p) {
  const int i = blockIdx.x;
  const int np = *npad_p;
  const int kend = ((i >> 7) + 1) << 7;
  const u16* r0 = S0 + (size_t)i * SEQ;
  const u16* r1 = S1 + (size_t)i * SEQ;
  u16* arow = att + (size_t)i * SEQ;
  const int t = threadIdx.x;

  float m = -3.0e38f, s = 0.f;
  for (int j = np + t; j <= i; j += 256) {
    float v = bf2f(r0[j]) + bf2f(r1[j]);
    if (v > m) { s = s * __expf(m - v) + 1.f; m = v; }
    else       { s += __expf(v - m); }
  }
#pragma unroll
  for (int off = 32; off > 0; off >>= 1) {
    float mo = __shfl_xor(m, off);
    float so = __shfl_xor(s, off);
    float M = fmaxf(m, mo);
    s = s * __expf(m - M) + so * __expf(mo - M);
    m = M;
  }
  __shared__ float sm[4], ss[4];
  const int w = t >> 6, l = t & 63;
  if (l == 0) { sm[w] = m; ss[w] = s; }
  __syncthreads();
  const float M = fmaxf(fmaxf(sm[0], sm[1]), fmaxf(sm[2], sm[3]));
  const float Ssum = ss[0] * __expf(sm[0] - M) + ss[1] * __expf(sm[1] - M) +
                     ss[2] * __expf(sm[2] - M) + ss[3] * __expf(sm[3] - M);
  const float inv = 1.f / Ssum;  // padded rows masked to 0 below; inv unused there

  for (int j0b = t * 8; j0b < kend; j0b += 2048) {
    union { u16 s8[8]; uint4 v; } u;
#pragma unroll
    for (int q = 0; q < 8; ++q) {
      const int j = j0b + q;
      float a = 0.f;
      if (j >= np && j <= i)
        a = __expf(bf2f(r0[j]) + bf2f(r1[j]) - M) * inv;
      u.s8[q] = f2bf(a);
    }
    *(uint4*)(arow + j0b) = u.v;
  }
}

// ---------- launch ----------

extern "C" void kernel_launch(void* const* d_in, const int* in_sizes, int n_in,
                              void* d_out, int out_size, void* d_ws, size_t ws_size,
                              hipStream_t stream) {
  const float* x = (const float*)d_in[0];
  const float* W = (const float*)d_in[1];
  const float* b = (const float*)d_in[2];
  const int* npad = (const int*)d_in[3];
  float* out = (float*)d_out;

  // workspace:
  // [xb 16.8 | Wt 25.2] reused as att 33.6 ][ qkvb 50.3 ][ vt 16.8 ][ sc0 33.6 | sc1 33.6 ] MB
  // sc0/sc1 hold bf16 score partials for softmax, then are reused as the two
  // fp32 GEMM3 output partials (each exactly SEQ*FEAT*4 = 33.6 MB).
  char* p = (char*)d_ws;
  u16* xb = (u16*)p;
  u16* Wt = (u16*)(p + (size_t)SEQ * FEAT * 2);
  u16* att = (u16*)p;
  p += (size_t)SEQ * FEAT * 2 + (size_t)F3 * FEAT * 2;
  u16* qkvb = (u16*)p;  p += (size_t)SEQ * F3 * 2;
  u16* vt   = (u16*)p;  p += (size_t)FEAT * SEQ * 2;
  u16* sc0  = (u16*)p;  p += (size_t)SEQ * SEQ * 2;   // bf16 split-K partial 0
  u16* sc1  = (u16*)p;  p += (size_t)SEQ * SEQ * 2;   // bf16 split-K partial 1
  float* op = (float*)sc0;                            // fp32 out-partials (2x)
  if (ws_size < (size_t)(p - (char*)d_ws)) return;

  const float scale = 0.02209708691207961f;  // 1/sqrt(2048)

  cvt_f32_bf16<<<SEQ * FEAT / 8 / 256, 256, 0, stream>>>(x, xb, SEQ * FEAT / 8);
  transp_f2b<<<dim3(F3 / 32, FEAT / 32), dim3(32, 8), 0, stream>>>(W, F3, Wt, FEAT);
  // qkv = x @ W + b (bf16)
  gemm_bt<1, 1, 0><<<dim3(F3 / 128, SEQ / 128), 256, 0, stream>>>(
      xb, FEAT, Wt, FEAT, (void*)qkvb, F3, FEAT, b, 1.0f);
  transp_b2b<<<dim3(FEAT / 32, SEQ / 32), dim3(32, 8), 0, stream>>>(
      qkvb + 2 * FEAT, F3, vt, SEQ);
  // scores = (q @ k^T) / sqrt(F): triangle over bi,bj>=1 x split-K=2 -> sc0/sc1
  gemm_bt<1, 0, 1><<<dim3(31 * 32 / 2, 1, 2), 256, 0, stream>>>(
      qkvb, F3, qkvb + FEAT, F3, (void*)sc0, SEQ, FEAT, nullptr, scale);
  softmax_rows<<<SEQ, 256, 0, stream>>>(sc0, sc1, att, npad);
  // out partials = att @ v: causal split-K=2, disjoint fp32 buffers (no atomics)
  gemm_bt<0, 0, 2><<<dim3(FEAT / 128, SEQ / 128, 2), 256, 0, stream>>>(
      att, SEQ, vt, SEQ, (void*)op, FEAT, 0, nullptr, 1.0f);
  // out = p0 + p1
  reduce_add<<<SEQ * FEAT / 4 / 256, 256, 0, stream>>>(
      op, op + (size_t)SEQ * FEAT, out, SEQ * FEAT / 4);
}